// Round 10
// baseline (236.673 us; speedup 1.0000x reference)
//
#include <hip/hip_runtime.h>
#include <math.h>

// ProjectionLayer: out[b,t,gx,gy] = data[b,t, argmin_n ||locs[b,n]*25+25 - (gx,gy)|| ]
// B=64, T=1024, N=256 sensors, G=50 (2500 grid cells).
// SINGLE fused kernel: 128 blocks x 512 thr, each block owns a CONTIGUOUS
//   5.12 MB output slab (XCD-contiguous mapping). Per block: recompute the
//   batch argmin (cheap VALU, hidden under chunk-0 prefetch), then LDS-staged
//   gather with t-interleaved b128 reads (4 t-values/read), coalesced float4
//   stores. 655 MB W + 67 MB R.
// R1: scattered GLOBAL loads ~1 lane/cyc in TA -> LDS.      (407->200 us)
// R2/R4: TLP 4->8 blocks/CU NEUTRAL.                        (200->207)
// R5: drain-free barriers NEUTRAL (at 8 blocks/CU).         (207)
// R6: b128 LDS gather NEUTRAL at 2048 blocks.               (209)
// R7 WIN: 256 long contiguous write streams (1/CU).         (209->179)
// R8: 512 streams regressed; R9: 128 streams 175. Monotone stream curve:
//   2048:209 / 1024:200 / 512:194 / 256:179 / 128:175 -> near asymptote.
// R10: fuse argmin (kill 2nd dispatch + launch gap) + b128 gather (LDS-pipe
//   48->25 us/CU, visible at 128 CUs where per-CU LDS work doubled).

#define GRIDG  50
#define GG     2500   // GRIDG*GRIDG
#define GQ     625    // GG/4 (float4 groups per output row)
#define NS     256    // sensors
#define TT     1024
#define BB     64
#define TCHUNK 512    // t rows per block (5.12 MB contiguous slab)
#define RSTG   32     // rows staged in LDS per barrier (8 subtiles of 4 rows)
#define NCH    (TCHUNK / RSTG)   // 16

typedef float f32x4 __attribute__((ext_vector_type(4)));

// exact replication of reference fp32 arithmetic: unfused mul/add + rounded sqrt
__device__ __forceinline__ float ref_dist(float lx, float ly, float gx, float gy) {
    const float dx = lx - gx;
    const float dy = ly - gy;
    const float s  = __fadd_rn(__fmul_rn(dx, dx), __fmul_rn(dy, dy));
    return __fsqrt_rn(s);
}

// ---- fused: argmin + slab gather --------------------------------------------
__global__ __launch_bounds__(512) void proj_fused_k(const float* __restrict__ data,
                                                    const float* __restrict__ locs,
                                                    float* __restrict__ out) {
    __shared__ float lsx[NS];
    __shared__ float lsy[NS];
    __shared__ int   nearest_l[GG];      // 10 KB
    __shared__ float rows4[RSTG * NS];   // 32 KB, t-interleaved subtiles
    const int tid = threadIdx.x;
    const int l   = blockIdx.x;
    // XCD-contiguous slab mapping: XCD k (blocks l%8==k) covers batches
    // [8k, 8k+8) -> one contiguous 80 MB output region per XCD.
    const int sb  = (l & 7) * 16 + (l >> 3);   // 128 slabs
    const int b   = sb >> 1;                   // batch
    const int t0  = (sb & 1) * TCHUNK;         // half of T

    // load + scale this batch's sensor locations into LDS
    if (tid < NS) {
        const float2 lc = ((const float2*)locs)[b * NS + tid];
        lsx[tid] = __fadd_rn(__fmul_rn(lc.x, 25.0f), 25.0f);
        lsy[tid] = __fadd_rn(__fmul_rn(lc.y, 25.0f), 25.0f);
    }

    // issue chunk-0 prefetch FIRST: HBM latency hides under the argmin VALU.
    // wave w stages subtile w (4 t-rows); lane covers 4 sensors (f32x4).
    const int wav  = tid >> 6;
    const int lane = tid & 63;
    const f32x4* __restrict__ dbase = (const f32x4*)data + (size_t)b * TT * (NS / 4);
    f32x4 pr[4];
    {
        const f32x4* __restrict__ s0 = dbase + (size_t)(t0 + 4 * wav) * (NS / 4) + lane;
        #pragma unroll
        for (int rr = 0; rr < 4; ++rr) pr[rr] = s0[rr * (NS / 4)];
    }
    __syncthreads();   // locs visible

    // per-block argmin recompute (ascending n + strict '<' == jnp.argmin tie-break)
    for (int g = tid; g < GG; g += 512) {
        const float gx = (float)(g / GRIDG);
        const float gy = (float)(g % GRIDG);
        float best = 1.0e30f;
        int   bi   = 0;
        #pragma unroll 4
        for (int n = 0; n < NS; ++n) {
            const float d = ref_dist(lsx[n], lsy[n], gx, gy);
            if (d < best) { best = d; bi = n; }
        }
        nearest_l[g] = bi;
    }
    __syncthreads();   // indices visible

    // per-thread gather indices (loop-invariant over t) -> registers
    const int4 iv0 = ((const int4*)nearest_l)[tid];            // tid < 512 <= GQ
    const int4 iv1 = (tid < GQ - 512)
                   ? ((const int4*)nearest_l)[512 + tid]
                   : make_int4(0, 0, 0, 0);

    float4* __restrict__ obase = (float4*)out + (size_t)b * TT * GQ;
    f32x4*  __restrict__ lds4  = (f32x4*)rows4;

    for (int c = 0; c < NCH; ++c) {
        __syncthreads();   // previous chunk fully consumed
        // commit prefetched rows to LDS, 4x4 transposed: subtile wav holds
        // element (n, rr) at f32x4 index wav*256 + n  (n = 4*lane+k)
        #pragma unroll
        for (int k = 0; k < 4; ++k) {
            f32x4 w;
            w.x = pr[0][k]; w.y = pr[1][k]; w.z = pr[2][k]; w.w = pr[3][k];
            lds4[wav * 256 + lane * 4 + k] = w;
        }
        // issue next chunk's loads early (in flight across the gather below)
        if (c + 1 < NCH) {
            const f32x4* __restrict__ s1 =
                dbase + (size_t)(t0 + (c + 1) * RSTG + 4 * wav) * (NS / 4) + lane;
            #pragma unroll
            for (int rr = 0; rr < 4; ++rr) pr[rr] = s1[rr * (NS / 4)];
        }
        __syncthreads();   // staged rows visible

        const int ts = t0 + c * RSTG;
        #pragma unroll
        for (int r4 = 0; r4 < RSTG / 4; ++r4) {          // 8 subtiles of 4 rows
            const f32x4* __restrict__ tile = lds4 + r4 * 256;
            // one b128 read per grid cell: 4 t-values
            const f32x4 g0 = tile[iv0.x];
            const f32x4 g1 = tile[iv0.y];
            const f32x4 g2 = tile[iv0.z];
            const f32x4 g3 = tile[iv0.w];
            #pragma unroll
            for (int rr = 0; rr < 4; ++rr) {             // transpose -> row stores
                float4 v;
                v.x = g0[rr]; v.y = g1[rr]; v.z = g2[rr]; v.w = g3[rr];
                obase[(size_t)(ts + r4 * 4 + rr) * GQ + tid] = v;
            }
            if (tid < GQ - 512) {
                const f32x4 h0 = tile[iv1.x];
                const f32x4 h1 = tile[iv1.y];
                const f32x4 h2 = tile[iv1.z];
                const f32x4 h3 = tile[iv1.w];
                #pragma unroll
                for (int rr = 0; rr < 4; ++rr) {
                    float4 u;
                    u.x = h0[rr]; u.y = h1[rr]; u.z = h2[rr]; u.w = h3[rr];
                    obase[(size_t)(ts + r4 * 4 + rr) * GQ + 512 + tid] = u;
                }
            }
        }
    }
}

extern "C" void kernel_launch(void* const* d_in, const int* in_sizes, int n_in,
                              void* d_out, int out_size, void* d_ws, size_t ws_size,
                              hipStream_t stream) {
    const float* data = (const float*)d_in[0];   // [64,1024,256] f32
    const float* locs = (const float*)d_in[1];   // [64,256,2]    f32
    float*       out  = (float*)d_out;           // [64,1024,50,50] f32
    (void)in_sizes; (void)n_in; (void)out_size; (void)d_ws; (void)ws_size;

    proj_fused_k<<<dim3(BB * 2), 512, 0, stream>>>(data, locs, out);
}

// Round 11
// 222.583 us; speedup vs baseline: 1.0633x; 1.0633x over previous
//
#include <hip/hip_runtime.h>
#include <math.h>

// ProjectionLayer: out[b,t,gx,gy] = data[b,t, argmin_n ||locs[b,n]*25+25 - (gx,gy)|| ]
// B=64, T=1024, N=256 sensors, G=50 (2500 grid cells).
// Stage 1 (nearest_k): 41M distance evals -> nearest[b,g] in d_ws (640 KB).
// Stage 2 (gather_lds_k): 128 blocks x 512 thr, each block owns a CONTIGUOUS
//   5.12 MB output slab (XCD-contiguous mapping); DOUBLE-BUFFERED LDS staging
//   with ONE lgkm-only raw barrier per chunk (prefetch loads + stores stay in
//   flight across barriers); b32 LDS gather; coalesced float4 stores.
// R1: scattered GLOBAL loads ~1 lane/cyc in TA -> LDS.      (407->200 us)
// R2/R4: TLP 4->8 blocks/CU NEUTRAL.                        (200->207)
// R5: drain-free barriers NEUTRAL at 8 blocks/CU.           (207)
// R6: b128 LDS gather NEUTRAL at 2048 blocks.               (209)
// R7 WIN: 256 long contiguous write streams (1/CU).         (209->179)
// R8/R9: stream curve 2048:209/1024:200/512:194/256:179/128:175.
// R10: fused argmin + 4x4-transposed LDS commit REGRESSED (237): the
//   transpose write (lane stride 64B) is a ~32-way bank conflict, and at
//   ~1 block/CU the argmin prologue is fully exposed. Verdicts from high-
//   occupancy rounds (R5/R6 "neutral") do NOT transfer to 1 block/CU.
// R11: R9 exactly + dbuf + single lgkm-only barrier per chunk: at 1 block/CU
//   the 2x-per-chunk vmcnt(0) drains (32/block) expose prefetch+store
//   latency with nothing to cover it. Safety: a buffer is rewritten only
//   after a barrier every reader reached AFTER its ds_reads completed
//   (reads feed stores issued pre-barrier).

#define GRIDG  50
#define GG     2500   // GRIDG*GRIDG
#define GQ     625    // GG/4 (float4 groups per output row)
#define NS     256    // sensors
#define TT     1024
#define BB     64
#define TCHUNK 512    // t rows per block (5.12 MB contiguous slab)
#define RSTG   32     // rows staged per LDS buffer (32 KB)
#define NCH    (TCHUNK / RSTG)   // 16

// post-ds_write barrier: LDS visibility only; global loads/stores NOT drained
#define BAR_LDS()  asm volatile("s_waitcnt lgkmcnt(0)\n\ts_barrier" ::: "memory")

// exact replication of reference fp32 arithmetic: unfused mul/add + rounded sqrt
__device__ __forceinline__ float ref_dist(float lx, float ly, float gx, float gy) {
    const float dx = lx - gx;
    const float dy = ly - gy;
    const float s  = __fadd_rn(__fmul_rn(dx, dx), __fmul_rn(dy, dy));
    return __fsqrt_rn(s);
}

// ---- Stage 1: nearest sensor index per grid cell -----------------------------
__global__ __launch_bounds__(256) void nearest_k(const float* __restrict__ locs,
                                                 int* __restrict__ nearest) {
    __shared__ float lsx[NS];
    __shared__ float lsy[NS];
    const int b   = blockIdx.x / 10;   // 10 blocks of 256 cover 2500 cells
    const int gc  = blockIdx.x % 10;
    const int tid = threadIdx.x;

    const float2 l = ((const float2*)locs)[b * NS + tid];
    lsx[tid] = __fadd_rn(__fmul_rn(l.x, 25.0f), 25.0f);
    lsy[tid] = __fadd_rn(__fmul_rn(l.y, 25.0f), 25.0f);
    __syncthreads();

    const int g = gc * 256 + tid;
    if (g >= GG) return;
    const float gx = (float)(g / GRIDG);
    const float gy = (float)(g % GRIDG);

    float best = 1.0e30f;
    int   bi   = 0;
    #pragma unroll 4
    for (int n = 0; n < NS; ++n) {          // ascending n + strict '<'  => first-index
        const float d = ref_dist(lsx[n], lsy[n], gx, gy);   //    tie-break == jnp.argmin
        if (d < best) { best = d; bi = n; }
    }
    nearest[b * GG + g] = bi;
}

// ---- Stage 2: 5.12 MB slab per block, dbuf LDS, 1 lgkm-only barrier/chunk ---
__global__ __launch_bounds__(512) void gather_lds_k(const float* __restrict__ data,
                                                    const int* __restrict__ nearest,
                                                    float* __restrict__ out) {
    __shared__ float rows[2][RSTG * NS];   // 2 x 32 KB
    const int tid = threadIdx.x;
    const int l   = blockIdx.x;
    // XCD-contiguous slab mapping: XCD k (blocks l%8==k) covers batches
    // [8k, 8k+8) -> one contiguous 80 MB output region per XCD.
    const int sb  = (l & 7) * 16 + (l >> 3);   // 128 slabs
    const int b   = sb >> 1;                   // batch
    const int t0  = (sb & 1) * TCHUNK;         // half of T

    // per-thread gather indices (loop-invariant over t) -> registers
    const int4 iv0 = ((const int4*)nearest)[b * GQ + tid];          // tid<512<=GQ
    const int4 iv1 = (tid < GQ - 512)
                   ? ((const int4*)nearest)[b * GQ + 512 + tid]
                   : make_int4(0, 0, 0, 0);

    const float4* __restrict__ dbase = (const float4*)data + (size_t)b * TT * (NS / 4);
    float4*       __restrict__ obase = (float4*)out + (size_t)b * TT * GQ;

    // prologue prefetch: chunk 0 (32 rows = 2048 float4 = 4/thread, coalesced)
    const float4* __restrict__ src = dbase + (size_t)t0 * (NS / 4);
    float4 pr[4];
    #pragma unroll
    for (int i = 0; i < 4; ++i) pr[i] = src[tid + i * 512];

    for (int c = 0; c < NCH; ++c) {
        // commit prefetched chunk to LDS buffer c&1 (row-major, conflict-free;
        // vmcnt waits land here, hidden under previous chunk's gather stores)
        float4* __restrict__ buf = (float4*)rows[c & 1];
        #pragma unroll
        for (int i = 0; i < 4; ++i) buf[tid + i * 512] = pr[i];
        // issue next chunk's loads early (in flight across barrier + gather)
        if (c + 1 < NCH) {
            src += RSTG * (NS / 4);
            #pragma unroll
            for (int i = 0; i < 4; ++i) pr[i] = src[tid + i * 512];
        }
        BAR_LDS();   // single barrier per chunk; global loads/stores in flight
        // dbuf safety: buf[c&1] was last read in chunk c-2; those ds_reads
        // fed stores issued before barrier(c-1), so they completed before
        // every wave passed that barrier -- rewrite here cannot race them.

        const int ts = t0 + c * RSTG;
        #pragma unroll 4
        for (int r = 0; r < RSTG; ++r) {
            const float* __restrict__ row  = rows[c & 1] + r * NS;
            float4*      __restrict__ orow = obase + (size_t)(ts + r) * GQ;
            float4 v;
            v.x = row[iv0.x]; v.y = row[iv0.y]; v.z = row[iv0.z]; v.w = row[iv0.w];
            orow[tid] = v;                          // coalesced 16B/lane store
            if (tid < GQ - 512) {
                float4 u;
                u.x = row[iv1.x]; u.y = row[iv1.y]; u.z = row[iv1.z]; u.w = row[iv1.w];
                orow[512 + tid] = u;
            }
        }
    }
}

// ---- Fallback: fused (only if ws too small for the 640 KB index buffer) -----
__global__ __launch_bounds__(256) void fused_k(const float* __restrict__ data,
                                               const float* __restrict__ locs,
                                               float* __restrict__ out) {
    __shared__ float lsx[NS];
    __shared__ float lsy[NS];
    const int b   = blockIdx.z;
    const int tid = threadIdx.x;
    const float2 l = ((const float2*)locs)[b * NS + tid];
    lsx[tid] = __fadd_rn(__fmul_rn(l.x, 25.0f), 25.0f);
    lsy[tid] = __fadd_rn(__fmul_rn(l.y, 25.0f), 25.0f);
    __syncthreads();

    const int gq = blockIdx.x * 256 + tid;
    if (gq >= GQ) return;

    int iv[4];
    #pragma unroll
    for (int k = 0; k < 4; ++k) {
        const int g  = gq * 4 + k;
        const float gx = (float)(g / GRIDG);
        const float gy = (float)(g % GRIDG);
        float best = 1.0e30f;
        int   bi   = 0;
        for (int n = 0; n < NS; ++n) {
            const float d = ref_dist(lsx[n], lsy[n], gx, gy);
            if (d < best) { best = d; bi = n; }
        }
        iv[k] = bi;
    }

    const int t0 = blockIdx.y * (TT / 2);
    const float* __restrict__ dbase = data + (size_t)b * TT * NS;
    float4*      __restrict__ obase = (float4*)out + (size_t)b * TT * GQ + gq;
    #pragma unroll 4
    for (int t = t0; t < t0 + TT / 2; ++t) {
        const float* __restrict__ row = dbase + t * NS;
        float4 v;
        v.x = row[iv[0]];
        v.y = row[iv[1]];
        v.z = row[iv[2]];
        v.w = row[iv[3]];
        obase[(size_t)t * GQ] = v;
    }
}

extern "C" void kernel_launch(void* const* d_in, const int* in_sizes, int n_in,
                              void* d_out, int out_size, void* d_ws, size_t ws_size,
                              hipStream_t stream) {
    const float* data = (const float*)d_in[0];   // [64,1024,256] f32
    const float* locs = (const float*)d_in[1];   // [64,256,2]    f32
    float*       out  = (float*)d_out;           // [64,1024,50,50] f32
    (void)in_sizes; (void)n_in; (void)out_size;

    const size_t idx_bytes = (size_t)BB * GG * sizeof(int);   // 640 KB
    if (ws_size >= idx_bytes) {
        int* nearest = (int*)d_ws;
        nearest_k<<<dim3(BB * 10), 256, 0, stream>>>(locs, nearest);
        gather_lds_k<<<dim3(BB * 2), 512, 0, stream>>>(data, nearest, out);
    } else {
        fused_k<<<dim3(3, 2, BB), 256, 0, stream>>>(data, locs, out);
    }
}

// Round 12
// 219.728 us; speedup vs baseline: 1.0771x; 1.0130x over previous
//
#include <hip/hip_runtime.h>
#include <math.h>

// ProjectionLayer: out[b,t,gx,gy] = data[b,t, argmin_n ||locs[b,n]*25+25 - (gx,gy)|| ]
// B=64, T=1024, N=256 sensors, G=50 (2500 grid cells).
// Stage 1 (nearest_k): 41M distance evals -> nearest[b,g] in d_ws (640 KB).
// Stage 2 (gather_lds_k): 256 blocks x 512 thr; each block = 2 consecutive
//   slabs (same batch, contiguous 2.56 MB write region, XCD-contiguous
//   mapping). Per slab: stage the WHOLE 128 KB source (128 t-rows) into LDS
//   in ONE burst, then a pure-write gather phase (no global reads). Slab-2
//   loads prefetch-issued during slab-1 writes (R9 pattern).
// R1: scattered GLOBAL loads ~1 lane/cyc in TA -> LDS.      (407->200 us)
// R2/R4: TLP 4->8 blocks/CU NEUTRAL.                        (200->207)
// R5: drain-free barriers NEUTRAL at 8 blocks/CU.           (207)
// R6: b128 LDS gather NEUTRAL at 2048 blocks.               (209)
// R7 WIN: 256 long contiguous write streams (1/CU).         (209->179)
// R8/R9: stream curve 2048:209/1024:200/512:194/256:179/128:175.
// R10: fused argmin + transposed LDS commit (32-way conflict) REGRESSED (237).
// R11: dbuf + lgkm-only barrier REGRESSED (222) -> vmcnt(0) drain at the
//   barrier is harmless-to-helpful; store-queue micromanagement is a dead
//   axis. Plain __syncthreads + R9 prefetch is the proven scheme.
// R12 probe: stream count (2048..128) is confounded with read-burst
//   interleave frequency. Fix streams at 256, make read bursts 4x bigger
//   and 4x rarer (whole-slab 128KB staging). ~160-168 => interleave theory;
//   ~179 => stream-count theory; ~175 => burst size irrelevant.

#define GRIDG  50
#define GG     2500   // GRIDG*GRIDG
#define GQ     625    // GG/4 (float4 groups per output row)
#define NS     256    // sensors
#define TT     1024
#define BB     64
#define TSLAB  128    // t rows per slab (128 KB source, 1.28 MB output)

// exact replication of reference fp32 arithmetic: unfused mul/add + rounded sqrt
__device__ __forceinline__ float ref_dist(float lx, float ly, float gx, float gy) {
    const float dx = lx - gx;
    const float dy = ly - gy;
    const float s  = __fadd_rn(__fmul_rn(dx, dx), __fmul_rn(dy, dy));
    return __fsqrt_rn(s);
}

// ---- Stage 1: nearest sensor index per grid cell -----------------------------
__global__ __launch_bounds__(256) void nearest_k(const float* __restrict__ locs,
                                                 int* __restrict__ nearest) {
    __shared__ float lsx[NS];
    __shared__ float lsy[NS];
    const int b   = blockIdx.x / 10;   // 10 blocks of 256 cover 2500 cells
    const int gc  = blockIdx.x % 10;
    const int tid = threadIdx.x;

    const float2 l = ((const float2*)locs)[b * NS + tid];
    lsx[tid] = __fadd_rn(__fmul_rn(l.x, 25.0f), 25.0f);
    lsy[tid] = __fadd_rn(__fmul_rn(l.y, 25.0f), 25.0f);
    __syncthreads();

    const int g = gc * 256 + tid;
    if (g >= GG) return;
    const float gx = (float)(g / GRIDG);
    const float gy = (float)(g % GRIDG);

    float best = 1.0e30f;
    int   bi   = 0;
    #pragma unroll 4
    for (int n = 0; n < NS; ++n) {          // ascending n + strict '<'  => first-index
        const float d = ref_dist(lsx[n], lsy[n], gx, gy);   //    tie-break == jnp.argmin
        if (d < best) { best = d; bi = n; }
    }
    nearest[b * GG + g] = bi;
}

// ---- Stage 2: whole-slab LDS staging, pure-write gather phases --------------
__global__ __launch_bounds__(512) void gather_lds_k(const float* __restrict__ data,
                                                    const int* __restrict__ nearest,
                                                    float* __restrict__ out) {
    __shared__ float rows[TSLAB * NS];   // 128 KB: full slab source
    const int tid  = threadIdx.x;
    const int l    = blockIdx.x;
    // XCD-contiguous pair mapping: XCD k (blocks l%8==k) covers batches
    // [8k, 8k+8) -> one contiguous 80 MB output region per XCD.
    const int pair = (l & 7) * 32 + (l >> 3);   // 0..255
    const int s0   = pair * 2;                  // slabs s0, s0+1 (same batch)
    const int b    = s0 >> 3;                   // batch (8 slabs per batch)

    // per-thread gather indices (loop-invariant over t) -> registers
    const int4 iv0 = ((const int4*)nearest)[b * GQ + tid];          // tid<512<=GQ
    const int4 iv1 = (tid < GQ - 512)
                   ? ((const int4*)nearest)[b * GQ + 512 + tid]
                   : make_int4(0, 0, 0, 0);

    const float4* __restrict__ dbase = (const float4*)data + (size_t)b * TT * (NS / 4);
    float4*       __restrict__ obase = (float4*)out + (size_t)b * TT * GQ;

    // prefetch slab 0 source (128 KB = 8192 float4 = 16/thread, coalesced burst)
    float4 pr[16];
    {
        const float4* __restrict__ src =
            dbase + (size_t)((s0 & 7) * TSLAB) * (NS / 4);
        #pragma unroll
        for (int i = 0; i < 16; ++i) pr[i] = src[tid + i * 512];
    }

    #pragma unroll
    for (int sl = 0; sl < 2; ++sl) {
        const int t0 = ((s0 + sl) & 7) * TSLAB;
        if (sl) __syncthreads();   // previous slab's gather reads done
        // commit staged slab to LDS (row-major, conflict-free)
        #pragma unroll
        for (int i = 0; i < 16; ++i) ((float4*)rows)[tid + i * 512] = pr[i];
        // issue next slab's load burst early (in flight across the writes)
        if (sl == 0) {
            const float4* __restrict__ src =
                dbase + (size_t)(((s0 + 1) & 7) * TSLAB) * (NS / 4);
            #pragma unroll
            for (int i = 0; i < 16; ++i) pr[i] = src[tid + i * 512];
        }
        __syncthreads();           // staged rows visible

        // pure-write phase: 128 rows, zero global reads
        #pragma unroll 4
        for (int r = 0; r < TSLAB; ++r) {
            const float* __restrict__ row  = rows + r * NS;
            float4*      __restrict__ orow = obase + (size_t)(t0 + r) * GQ;
            float4 v;
            v.x = row[iv0.x]; v.y = row[iv0.y]; v.z = row[iv0.z]; v.w = row[iv0.w];
            orow[tid] = v;                          // coalesced 16B/lane store
            if (tid < GQ - 512) {
                float4 u;
                u.x = row[iv1.x]; u.y = row[iv1.y]; u.z = row[iv1.z]; u.w = row[iv1.w];
                orow[512 + tid] = u;
            }
        }
    }
}

// ---- Fallback: fused (only if ws too small for the 640 KB index buffer) -----
__global__ __launch_bounds__(256) void fused_k(const float* __restrict__ data,
                                               const float* __restrict__ locs,
                                               float* __restrict__ out) {
    __shared__ float lsx[NS];
    __shared__ float lsy[NS];
    const int b   = blockIdx.z;
    const int tid = threadIdx.x;
    const float2 l = ((const float2*)locs)[b * NS + tid];
    lsx[tid] = __fadd_rn(__fmul_rn(l.x, 25.0f), 25.0f);
    lsy[tid] = __fadd_rn(__fmul_rn(l.y, 25.0f), 25.0f);
    __syncthreads();

    const int gq = blockIdx.x * 256 + tid;
    if (gq >= GQ) return;

    int iv[4];
    #pragma unroll
    for (int k = 0; k < 4; ++k) {
        const int g  = gq * 4 + k;
        const float gx = (float)(g / GRIDG);
        const float gy = (float)(g % GRIDG);
        float best = 1.0e30f;
        int   bi   = 0;
        for (int n = 0; n < NS; ++n) {
            const float d = ref_dist(lsx[n], lsy[n], gx, gy);
            if (d < best) { best = d; bi = n; }
        }
        iv[k] = bi;
    }

    const int t0 = blockIdx.y * (TT / 2);
    const float* __restrict__ dbase = data + (size_t)b * TT * NS;
    float4*      __restrict__ obase = (float4*)out + (size_t)b * TT * GQ + gq;
    #pragma unroll 4
    for (int t = t0; t < t0 + TT / 2; ++t) {
        const float* __restrict__ row = dbase + t * NS;
        float4 v;
        v.x = row[iv[0]];
        v.y = row[iv[1]];
        v.z = row[iv[2]];
        v.w = row[iv[3]];
        obase[(size_t)t * GQ] = v;
    }
}

extern "C" void kernel_launch(void* const* d_in, const int* in_sizes, int n_in,
                              void* d_out, int out_size, void* d_ws, size_t ws_size,
                              hipStream_t stream) {
    const float* data = (const float*)d_in[0];   // [64,1024,256] f32
    const float* locs = (const float*)d_in[1];   // [64,256,2]    f32
    float*       out  = (float*)d_out;           // [64,1024,50,50] f32
    (void)in_sizes; (void)n_in; (void)out_size;

    const size_t idx_bytes = (size_t)BB * GG * sizeof(int);   // 640 KB
    if (ws_size >= idx_bytes) {
        int* nearest = (int*)d_ws;
        nearest_k<<<dim3(BB * 10), 256, 0, stream>>>(locs, nearest);
        gather_lds_k<<<dim3(BB * 4), 512, 0, stream>>>(data, nearest, out);
    } else {
        fused_k<<<dim3(3, 2, BB), 256, 0, stream>>>(data, locs, out);
    }
}

// Round 13
// 156.772 us; speedup vs baseline: 1.5097x; 1.4016x over previous
//
#include <hip/hip_runtime.h>
#include <math.h>

// ProjectionLayer: out[b,t,gx,gy] = data[b,t, argmin_n ||locs[b,n]*25+25 - (gx,gy)|| ]
// B=64, T=1024, N=256 sensors, G=50 (2500 grid cells).
// Stage 1 (nearest_k): 41M distance evals -> nearest[b,g] in d_ws (640 KB).
// Stage 2 (sweep_gather_k): FILL-MIMIC device-wide dense sweep. Output rows
//   (G = b*1024+t, 10 KB each) interleaved across blocks in 8-row groups:
//   block j at iter s owns rows [s*2048 + j*8, +8) = 80 KB (128-B aligned,
//   no cross-block shared lines). All 256 blocks advance together -> ONE
//   dense ~20 MB write window + ~2 MB read window sweeping linearly, like
//   the 6.7 TB/s fillBuffer grid-stride sweep. dbuf 2x8 KB LDS, 1 sync/iter.
// R1: scattered GLOBAL loads ~1 lane/cyc in TA -> LDS.      (407->200 us)
// R2/R4: TLP 4->8 blocks/CU NEUTRAL.                        (200->207)
// R5: drain-free barriers NEUTRAL at 8 blocks/CU.           (207)
// R6: b128 LDS gather NEUTRAL at 2048 blocks.               (209)
// R7 WIN: 256 contiguous slabs (1/CU).                      (209->179)
// R8/R9: slab curve 512:194 / 256:179 / 128:175; gather time flat ~165
//   at 128 vs 256 slabs -> slab-count axis exhausted.
// R10: fused argmin + transposed LDS commit (bank conflict) REGRESSED (237).
// R11: dbuf + lgkm-only barrier at low occupancy REGRESSED (222).
// R12: whole-slab 128 KB staging REGRESSED (219) -> serialized read bursts
//   + 64-VGPR prefetch; burst-size axis dead.
// R13 theory: fill's 6.7 TB/s comes from a DENSE sweeping address window
//   (grid-stride), not from stream count. Interleave rows across blocks so
//   the device writes one dense window advancing in lockstep.

#define GRIDG  50
#define GG     2500   // GRIDG*GRIDG
#define GQ     625    // GG/4 (float4 groups per output row)
#define NS     256    // sensors
#define TT     1024
#define BB     64
#define NBLK   256    // sweep blocks
#define RPI    8      // rows per block per iteration (80 KB, 128-B aligned)
#define NIT    32     // iterations: 32*8*256 = 65536 rows = B*T

// exact replication of reference fp32 arithmetic: unfused mul/add + rounded sqrt
__device__ __forceinline__ float ref_dist(float lx, float ly, float gx, float gy) {
    const float dx = lx - gx;
    const float dy = ly - gy;
    const float s  = __fadd_rn(__fmul_rn(dx, dx), __fmul_rn(dy, dy));
    return __fsqrt_rn(s);
}

// ---- Stage 1: nearest sensor index per grid cell -----------------------------
__global__ __launch_bounds__(256) void nearest_k(const float* __restrict__ locs,
                                                 int* __restrict__ nearest) {
    __shared__ float lsx[NS];
    __shared__ float lsy[NS];
    const int b   = blockIdx.x / 10;   // 10 blocks of 256 cover 2500 cells
    const int gc  = blockIdx.x % 10;
    const int tid = threadIdx.x;

    const float2 l = ((const float2*)locs)[b * NS + tid];
    lsx[tid] = __fadd_rn(__fmul_rn(l.x, 25.0f), 25.0f);
    lsy[tid] = __fadd_rn(__fmul_rn(l.y, 25.0f), 25.0f);
    __syncthreads();

    const int g = gc * 256 + tid;
    if (g >= GG) return;
    const float gx = (float)(g / GRIDG);
    const float gy = (float)(g % GRIDG);

    float best = 1.0e30f;
    int   bi   = 0;
    #pragma unroll 4
    for (int n = 0; n < NS; ++n) {          // ascending n + strict '<'  => first-index
        const float d = ref_dist(lsx[n], lsy[n], gx, gy);   //    tie-break == jnp.argmin
        if (d < best) { best = d; bi = n; }
    }
    nearest[b * GG + g] = bi;
}

// ---- Stage 2: device-wide dense sweeping window -----------------------------
__global__ __launch_bounds__(512) void sweep_gather_k(const float* __restrict__ data,
                                                      const int* __restrict__ nearest,
                                                      float* __restrict__ out) {
    __shared__ float rows[2][RPI * NS];   // 2 x 8 KB double buffer
    const int tid = threadIdx.x;
    const int j   = blockIdx.x;           // 0..255

    const float4* __restrict__ data4 = (const float4*)data;  // row G = 64 float4
    float4*       __restrict__ out4  = (float4*)out;         // row G = 625 float4
    const int4*   __restrict__ nb    = (const int4*)nearest; // batch b = 625 int4

    // iteration-0 prefetch: 8 rows = 512 float4 = 1/thread, coalesced;
    // G0(s) = s*2048 + j*8 ; data byte addr = G*1024
    float4 pr = data4[(size_t)(j * RPI) * (NS / 4) + tid];
    // iteration-0 indices: b(s) = 2*s + (j>>7); all 8 rows share one batch
    int b = (j >> 7);
    int4 ivA = nb[(size_t)b * GQ + tid];
    int4 ivB = (tid < GQ - 512) ? nb[(size_t)b * GQ + 512 + tid]
                                : make_int4(0, 0, 0, 0);

    for (int s = 0; s < NIT; ++s) {
        // commit prefetched 8 rows to LDS buffer s&1 (contiguous, conflict-free)
        float* __restrict__ buf = rows[s & 1];
        ((float4*)buf)[tid] = pr;

        // issue next iteration's loads early (in flight across the stores)
        int4 ivA_n = ivA, ivB_n = ivB;
        if (s + 1 < NIT) {
            pr = data4[(size_t)((s + 1) * (NBLK * RPI) + j * RPI) * (NS / 4) + tid];
            const int bn = 2 * (s + 1) + (j >> 7);
            ivA_n = nb[(size_t)bn * GQ + tid];
            if (tid < GQ - 512) ivB_n = nb[(size_t)bn * GQ + 512 + tid];
        }
        __syncthreads();   // staged rows visible
        // dbuf safety: buf[s&1] was last read in iter s-2; readers passed the
        // sync at iter s-1 after their ds_reads completed -> no race.

        const size_t G0 = (size_t)s * (NBLK * RPI) + (size_t)j * RPI;
        #pragma unroll
        for (int r = 0; r < RPI; ++r) {
            const float* __restrict__ row  = buf + r * NS;
            float4*      __restrict__ orow = out4 + (G0 + r) * GQ;
            float4 v;
            v.x = row[ivA.x]; v.y = row[ivA.y]; v.z = row[ivA.z]; v.w = row[ivA.w];
            orow[tid] = v;                          // coalesced 16B/lane store
            if (tid < GQ - 512) {
                float4 u;
                u.x = row[ivB.x]; u.y = row[ivB.y]; u.z = row[ivB.z]; u.w = row[ivB.w];
                orow[512 + tid] = u;
            }
        }
        ivA = ivA_n; ivB = ivB_n;
    }
}

// ---- Fallback: fused (only if ws too small for the 640 KB index buffer) -----
__global__ __launch_bounds__(256) void fused_k(const float* __restrict__ data,
                                               const float* __restrict__ locs,
                                               float* __restrict__ out) {
    __shared__ float lsx[NS];
    __shared__ float lsy[NS];
    const int b   = blockIdx.z;
    const int tid = threadIdx.x;
    const float2 l = ((const float2*)locs)[b * NS + tid];
    lsx[tid] = __fadd_rn(__fmul_rn(l.x, 25.0f), 25.0f);
    lsy[tid] = __fadd_rn(__fmul_rn(l.y, 25.0f), 25.0f);
    __syncthreads();

    const int gq = blockIdx.x * 256 + tid;
    if (gq >= GQ) return;

    int iv[4];
    #pragma unroll
    for (int k = 0; k < 4; ++k) {
        const int g  = gq * 4 + k;
        const float gx = (float)(g / GRIDG);
        const float gy = (float)(g % GRIDG);
        float best = 1.0e30f;
        int   bi   = 0;
        for (int n = 0; n < NS; ++n) {
            const float d = ref_dist(lsx[n], lsy[n], gx, gy);
            if (d < best) { best = d; bi = n; }
        }
        iv[k] = bi;
    }

    const int t0 = blockIdx.y * (TT / 2);
    const float* __restrict__ dbase = data + (size_t)b * TT * NS;
    float4*      __restrict__ obase = (float4*)out + (size_t)b * TT * GQ + gq;
    #pragma unroll 4
    for (int t = t0; t < t0 + TT / 2; ++t) {
        const float* __restrict__ row = dbase + t * NS;
        float4 v;
        v.x = row[iv[0]];
        v.y = row[iv[1]];
        v.z = row[iv[2]];
        v.w = row[iv[3]];
        obase[(size_t)t * GQ] = v;
    }
}

extern "C" void kernel_launch(void* const* d_in, const int* in_sizes, int n_in,
                              void* d_out, int out_size, void* d_ws, size_t ws_size,
                              hipStream_t stream) {
    const float* data = (const float*)d_in[0];   // [64,1024,256] f32
    const float* locs = (const float*)d_in[1];   // [64,256,2]    f32
    float*       out  = (float*)d_out;           // [64,1024,50,50] f32
    (void)in_sizes; (void)n_in; (void)out_size;

    const size_t idx_bytes = (size_t)BB * GG * sizeof(int);   // 640 KB
    if (ws_size >= idx_bytes) {
        int* nearest = (int*)d_ws;
        nearest_k<<<dim3(BB * 10), 256, 0, stream>>>(locs, nearest);
        sweep_gather_k<<<dim3(NBLK), 512, 0, stream>>>(data, nearest, out);
    } else {
        fused_k<<<dim3(3, 2, BB), 256, 0, stream>>>(data, locs, out);
    }
}